// Round 6
// baseline (5007.688 us; speedup 1.0000x reference)
//
#include <hip/hip_runtime.h>
#include <cstdint>
#include <cstddef>

// ---------------------------------------------------------------------------
// AdaptiveLSTMBlockWrapper — round 6: A-only LDS with the round-3-PROVEN
// zero-conflict geometry (128B rows, 8x16B slots, slot^(row&7)); B operand
// loaded global->reg (L2-resident weights) + on-the-fly hi/lo split (VALU
// hides under MFMA); BK=64; ONE barrier + ONE vmcnt(0) per K-step with a
// full-K-step latency window. fp32 GEMM = 3-product split-f16 MFMA.
//
// Engine: 256x256 block, 8 waves (2M x 4N), wave tile 128 rows x 64 vcols.
// LDS: 2 buffers x (Ahi 32KB + Alo 32KB) = 128KB. 16 K-steps of K=64.
// Per kt: [issue glds(kt+1)] [cvt B(kt)] [issue B(kt+1)] [ds_read A frags +
// 192 MFMA] [vmcnt(0)] [barrier]. Loads have ~1 full kt to land.
// ---------------------------------------------------------------------------

typedef _Float16 f16;
typedef f16   f16x8 __attribute__((ext_vector_type(8)));
typedef f16   f16x4 __attribute__((ext_vector_type(4)));
typedef float f32x4 __attribute__((ext_vector_type(4)));

#define TSTEPS 12

// d_out float offsets
#define O_ACC   0u
#define O_H1    4194304u
#define O_C1    8388608u
#define O_H2    12582912u
#define O_C2    16777216u
#define O_PCOST 20971520u
#define O_PSTEP 20971521u

// ws byte offsets
#define WS_C1    (size_t)(0u)
#define WS_C2    ((size_t)16u<<20)
#define WS_H1HI0 ((size_t)32u<<20)
#define WS_H1HI1 ((size_t)40u<<20)
#define WS_H1LO0 ((size_t)48u<<20)
#define WS_H1LO1 ((size_t)56u<<20)
#define WS_H2HI0 ((size_t)64u<<20)
#define WS_H2HI1 ((size_t)72u<<20)
#define WS_H2LO0 ((size_t)80u<<20)
#define WS_H2LO1 ((size_t)88u<<20)
#define WS_ACTHI ((size_t)96u<<20)
#define WS_ACTLO ((size_t)104u<<20)
#define WS_MISC  ((size_t)112u<<20)

// LDS: 2 buffers; within a buffer: Ahi at 0 (32KB), Alo at 32768 (32KB)
#define SEC_ALO 32768
#define BUFSZ   65536

__device__ __forceinline__ float sigmoidf_(float x) { return 1.0f / (1.0f + expf(-x)); }

__device__ __forceinline__ void glds16(const void* g, void* l) {
    __builtin_amdgcn_global_load_lds(
        (const __attribute__((address_space(1))) unsigned int*)g,
        (__attribute__((address_space(3))) unsigned int*)l, 16, 0, 0);
}

// Grid: 256 blocks (16 m x 16 hc). XCD-major over hc: 2MB weight slab/XCD.
__device__ __forceinline__ void block_tile(int& m0, int& hc0) {
    const int bid = blockIdx.x;
    const int lid = (bid & 7) * 32 + (bid >> 3);
    m0  = (lid & 15) * 256;
    hc0 = (lid >> 4) * 64;
}

// ---------------------------------------------------------------------------
// acc += A(256 rows x 1024) * B(256 vcols x 1024)^T, split-f16 3-product.
// A: pre-split f16 pairs, staged via glds into LDS (128B rows, 8 slots of
//    16B, invariant: slot s of row r holds k-chunk s^(r&7)) — r3-proven.
// B: loaded straight to registers. B_PAIR: f16 hi/lo pairs; else fp32 +
//    split on the fly. vcol lv: g=(lv>>4)&3=nf, hcl=wnb*16+l15;
//    wrow = nf*1024 + hc0 + wnb*16 + l15.
// ---------------------------------------------------------------------------
template<bool B_PAIR>
__device__ __forceinline__ void passK64(
    const f16* __restrict__ Ahi, const f16* __restrict__ Alo,
    const f16* __restrict__ Bhi, const f16* __restrict__ Blo,
    const float* __restrict__ Bf32,
    int m0, int hc0, f32x4 (&acc)[8][4], char* sm)
{
    const int tid = threadIdx.x, lane = tid & 63, wid = tid >> 6;
    const int wm  = (wid >> 2) * 128;
    const int wnb = wid & 3;
    const int l15 = lane & 15, lk = lane >> 4;

    // ---- A fragment read offsets (per mf): row-dependent parts ----
    int rbase[8], rx[8];
#pragma unroll
    for (int mf = 0; mf < 8; ++mf) {
        const int row = wm + mf * 16 + l15;
        rbase[mf] = row * 128;
        rx[mf]    = row & 7;
    }

    // ---- A glds ops: 8 per wave. op o = wid*8+i: sec=o>>5, j=o&31 ----
    // chunk j = rows j*8..j*8+7 (1KB). lane l: row=j*8+(l>>3), slot=l&7,
    // global k-chunk = (l&7)^(l>>3). LDS base (wave-uniform) = sec*32768+j*1024.
    const f16* ga[8];
    int albase[8];
    {
        const int rl = lane >> 3, sl = lane & 7;
        const int gchunk = (sl ^ rl) * 8;     // f16 elems within the 128B k-window
#pragma unroll
        for (int i = 0; i < 8; ++i) {
            const int o = wid * 8 + i;
            const int sec = o >> 5, j = o & 31;
            const f16* base = (sec == 0) ? Ahi : Alo;
            ga[i] = base + (size_t)(m0 + j * 8 + rl) * 1024 + gchunk;
            albase[i] = sec * SEC_ALO + j * 1024;
        }
    }

    // ---- B addresses ----
    const int wrow0 = hc0 + wnb * 16 + l15;   // + nf*1024
    const float* pB32[4];
    const f16*   pBh[4];
    const f16*   pBl[4];
#pragma unroll
    for (int nf = 0; nf < 4; ++nf) {
        const size_t ro = (size_t)(nf * 1024 + wrow0) * 1024 + lk * 8;
        if constexpr (B_PAIR) { pBh[nf] = Bhi + ro; pBl[nf] = Blo + ro; }
        else                  { pB32[nf] = Bf32 + ro; }
    }

    // B register staging (one K-step deep)
    float4 breg[4][2][2];   // [nf][ks][half]  (fp32 mode)
    int4   bregh[4][2], bregl[4][2];   // (pair mode)

    auto issueA = [&](int kt, char* buf) {
#pragma unroll
        for (int i = 0; i < 8; ++i)
            glds16(ga[i] + kt * 64, buf + albase[i]);
    };
    auto issueB = [&](int kt) {
#pragma unroll
        for (int nf = 0; nf < 4; ++nf)
#pragma unroll
            for (int ks = 0; ks < 2; ++ks) {
                if constexpr (B_PAIR) {
                    bregh[nf][ks] = *(const int4*)(pBh[nf] + kt * 64 + ks * 32);
                    bregl[nf][ks] = *(const int4*)(pBl[nf] + kt * 64 + ks * 32);
                } else {
                    const float* p = pB32[nf] + kt * 64 + ks * 32;
                    breg[nf][ks][0] = *(const float4*)(p);
                    breg[nf][ks][1] = *(const float4*)(p + 4);
                }
            }
    };

    // ---- prologue: stage kt=0 ----
    issueA(0, sm);
    issueB(0);
    asm volatile("s_waitcnt vmcnt(0)" ::: "memory");
    __builtin_amdgcn_s_barrier();
    asm volatile("" ::: "memory");

#pragma unroll 1
    for (int kt = 0; kt < 16; ++kt) {
        char* bc = sm + (kt & 1) * BUFSZ;
        char* bn = sm + ((kt + 1) & 1) * BUFSZ;
        const bool pre = (kt < 15);

        if (pre) issueA(kt + 1, bn);   // after the barrier that closed kt-1 reads

        // convert B(kt) to hi/lo f16 fragments (B(kt) retired by prior vmcnt(0))
        f16x8 bh[4][2], bl[4][2];
#pragma unroll
        for (int nf = 0; nf < 4; ++nf)
#pragma unroll
            for (int ks = 0; ks < 2; ++ks) {
                if constexpr (B_PAIR) {
                    bh[nf][ks] = *(const f16x8*)&bregh[nf][ks];
                    bl[nf][ks] = *(const f16x8*)&bregl[nf][ks];
                } else {
                    const float* f0 = (const float*)&breg[nf][ks][0];
                    const float* f1 = (const float*)&breg[nf][ks][1];
                    f16x8 h, l;
#pragma unroll
                    for (int j = 0; j < 4; ++j) {
                        const f16 a = (f16)f0[j];
                        h[j] = a; l[j] = (f16)(f0[j] - (float)a);
                        const f16 b = (f16)f1[j];
                        h[4 + j] = b; l[4 + j] = (f16)(f1[j] - (float)b);
                    }
                    bh[nf][ks] = h; bl[nf][ks] = l;
                }
            }

        if (pre) issueB(kt + 1);       // after cvt (WAR on breg)

        // compute: per ks, read A frags then 96 MFMAs
#pragma unroll
        for (int ks = 0; ks < 2; ++ks) {
            f16x8 ah[8], al[8];
#pragma unroll
            for (int mf = 0; mf < 8; ++mf) {
                const int off = rbase[mf] + ((((ks << 2) | lk) ^ rx[mf]) << 4);
                ah[mf] = *(const f16x8*)(bc + off);
                al[mf] = *(const f16x8*)(bc + SEC_ALO + off);
            }
#pragma unroll
            for (int nf = 0; nf < 4; ++nf)
#pragma unroll
                for (int mf = 0; mf < 8; ++mf) {
                    acc[mf][nf] = __builtin_amdgcn_mfma_f32_16x16x32_f16(ah[mf], bh[nf][ks], acc[mf][nf], 0, 0, 0);
                    acc[mf][nf] = __builtin_amdgcn_mfma_f32_16x16x32_f16(ah[mf], bl[nf][ks], acc[mf][nf], 0, 0, 0);
                    acc[mf][nf] = __builtin_amdgcn_mfma_f32_16x16x32_f16(al[mf], bh[nf][ks], acc[mf][nf], 0, 0, 0);
                }
        }

        // K-step boundary: my glds(kt+1)/B(kt+1) landed, then block-wide sync
        asm volatile("s_waitcnt vmcnt(0)" ::: "memory");
        if (pre) {
            __builtin_amdgcn_s_barrier();
            asm volatile("" ::: "memory");
        }
    }
}

// Z1 = x@W1^T + b_ih1 + b_hh1 (x pairs staged; W1 pairs direct-to-reg)
__global__ __launch_bounds__(512) void k_z1(
    const f16* __restrict__ xhi, const f16* __restrict__ xlo,
    const f16* __restrict__ W1hi, const f16* __restrict__ W1lo,
    const float* __restrict__ bih1, const float* __restrict__ bhh1,
    float* __restrict__ Z1)
{
    __shared__ __align__(16) char sm[2 * BUFSZ];
    int m0, hc0; block_tile(m0, hc0);
    f32x4 acc[8][4];
#pragma unroll
    for (int a = 0; a < 8; ++a)
#pragma unroll
        for (int b = 0; b < 4; ++b) acc[a][b] = (f32x4){0.f, 0.f, 0.f, 0.f};
    passK64<true>(xhi, xlo, W1hi, W1lo, nullptr, m0, hc0, acc, sm);

    const int tid = threadIdx.x, lane = tid & 63, wid = tid >> 6;
    const int wm = (wid >> 2) * 128, wnb = wid & 3, l15 = lane & 15, lk = lane >> 4;
    const int hc = hc0 + wnb * 16 + l15;
#pragma unroll
    for (int mf = 0; mf < 8; ++mf)
#pragma unroll
        for (int r = 0; r < 4; ++r) {
            const int row = m0 + wm + mf * 16 + lk * 4 + r;
#pragma unroll
            for (int g = 0; g < 4; ++g) {
                const int R = g * 1024 + hc;
                Z1[(size_t)row * 4096 + R] = acc[mf][g][r] + bih1[R] + bhh1[R];
            }
        }
}

// Layer-1 cell: gates = Z1 (+flag col @step0) + h1@Whh1^T
__global__ __launch_bounds__(512) void k_stepA(
    const float* __restrict__ Z1, const float* __restrict__ Whh1,
    const f16* __restrict__ h1hi_in, const f16* __restrict__ h1lo_in,
    const float* __restrict__ flagcol, float* __restrict__ c1,
    f16* __restrict__ h1hi_out, f16* __restrict__ h1lo_out,
    f16* __restrict__ acthi, f16* __restrict__ actlo,
    const unsigned* __restrict__ cnt_prev, int step)
{
    if (step > 0 && cnt_prev[0] == 0u) return;
    __shared__ __align__(16) char sm[2 * BUFSZ];
    int m0, hc0; block_tile(m0, hc0);
    f32x4 acc[8][4];
#pragma unroll
    for (int a = 0; a < 8; ++a)
#pragma unroll
        for (int b = 0; b < 4; ++b) acc[a][b] = (f32x4){0.f, 0.f, 0.f, 0.f};
    if (step > 0)
        passK64<false>(h1hi_in, h1lo_in, nullptr, nullptr, Whh1, m0, hc0, acc, sm);

    const int tid = threadIdx.x, lane = tid & 63, wid = tid >> 6;
    const int wm = (wid >> 2) * 128, wnb = wid & 3, l15 = lane & 15, lk = lane >> 4;
    const int hc = hc0 + wnb * 16 + l15;
#pragma unroll
    for (int mf = 0; mf < 8; ++mf)
#pragma unroll
        for (int r = 0; r < 4; ++r) {
            const int row = m0 + wm + mf * 16 + lk * 4 + r;
            float p[4];
#pragma unroll
            for (int g = 0; g < 4; ++g) {
                const int R = g * 1024 + hc;
                p[g] = acc[mf][g][r] + Z1[(size_t)row * 4096 + R];
                if (step == 0) p[g] += flagcol[R];
            }
            const float ig = sigmoidf_(p[0]);
            const float fg = sigmoidf_(p[1]);
            const float gg = tanhf(p[2]);
            const float og = sigmoidf_(p[3]);
            const int idx = row * 1024 + hc;
            const float cold = (step == 0) ? 0.0f : c1[idx];
            const float cn = fg * cold + ig * gg;
            c1[idx] = cn;
            const float h = og * tanhf(cn);
            const f16 hh = (f16)h;
            const f16 hl = (f16)(h - (float)hh);
            h1hi_out[idx] = hh; h1lo_out[idx] = hl;
            const bool pos = h > 0.0f;
            acthi[idx] = pos ? hh : (f16)0.0f;
            actlo[idx] = pos ? hl : (f16)0.0f;
        }
}

// Layer-2 cell: gates = b2 + act@Wih2^T + h2@Whh2^T
__global__ __launch_bounds__(512) void k_stepB(
    const f16* __restrict__ acthi, const f16* __restrict__ actlo,
    const float* __restrict__ Wih2,
    const f16* __restrict__ h2hi_in, const f16* __restrict__ h2lo_in,
    const float* __restrict__ Whh2,
    const float* __restrict__ bih2, const float* __restrict__ bhh2,
    float* __restrict__ c2, f16* __restrict__ h2hi_out, f16* __restrict__ h2lo_out,
    const unsigned* __restrict__ cnt_prev, int step)
{
    if (step > 0 && cnt_prev[0] == 0u) return;
    __shared__ __align__(16) char sm[2 * BUFSZ];
    int m0, hc0; block_tile(m0, hc0);
    f32x4 acc[8][4];
#pragma unroll
    for (int a = 0; a < 8; ++a)
#pragma unroll
        for (int b = 0; b < 4; ++b) acc[a][b] = (f32x4){0.f, 0.f, 0.f, 0.f};
    passK64<false>(acthi, actlo, nullptr, nullptr, Wih2, m0, hc0, acc, sm);
    if (step > 0)
        passK64<false>(h2hi_in, h2lo_in, nullptr, nullptr, Whh2, m0, hc0, acc, sm);

    const int tid = threadIdx.x, lane = tid & 63, wid = tid >> 6;
    const int wm = (wid >> 2) * 128, wnb = wid & 3, l15 = lane & 15, lk = lane >> 4;
    const int hc = hc0 + wnb * 16 + l15;
#pragma unroll
    for (int mf = 0; mf < 8; ++mf)
#pragma unroll
        for (int r = 0; r < 4; ++r) {
            const int row = m0 + wm + mf * 16 + lk * 4 + r;
            float p[4];
#pragma unroll
            for (int g = 0; g < 4; ++g) {
                const int R = g * 1024 + hc;
                p[g] = acc[mf][g][r] + bih2[R] + bhh2[R];
            }
            const float ig = sigmoidf_(p[0]);
            const float fg = sigmoidf_(p[1]);
            const float gg = tanhf(p[2]);
            const float og = sigmoidf_(p[3]);
            const int idx = row * 1024 + hc;
            const float cold = (step == 0) ? 0.0f : c2[idx];
            const float cn = fg * cold + ig * gg;
            c2[idx] = cn;
            const float h = og * tanhf(cn);
            const f16 hh = (f16)h;
            h2hi_out[idx] = hh;
            h2lo_out[idx] = (f16)(h - (float)hh);
        }
}

// Merged halting state machine + acc_out accumulate (one wave per row).
__global__ __launch_bounds__(256) void k_haltacc(
    const f16* __restrict__ h2hi, const f16* __restrict__ h2lo,
    const float* __restrict__ Whalt, const float* __restrict__ bhalt,
    float* __restrict__ halt, float* __restrict__ cont,
    float* __restrict__ ponder_out, unsigned* __restrict__ ctrl,
    float* __restrict__ acc_out,
    const unsigned* __restrict__ cnt_prev, int step)
{
    if (step > 0 && cnt_prev[0] == 0u) return;
    const int lane = threadIdx.x & 63;
    const int b = blockIdx.x * 4 + (threadIdx.x >> 6);
    const size_t base = (size_t)b * 1024;
    float sum = 0.0f;
    for (int k = lane; k < 1024; k += 64)
        sum += ((float)h2hi[base + k] + (float)h2lo[base + k]) * Whalt[k];
#pragma unroll
    for (int off = 32; off > 0; off >>= 1) sum += __shfl_down(sum, off, 64);
    float co = 0.0f;
    if (lane == 0) {
        const float sh = sigmoidf_(sum + bhalt[0]);
        if (cont[b] != 0.0f) {
            const float hn = halt[b] + sh;
            const bool ending = hn > 0.99f;
            co = sh + (ending ? (1.0f - hn) : 0.0f);
            halt[b] = hn;
            if (!ending) {
                ponder_out[b] += 1.0f;
                atomicAdd(&ctrl[step], 1u);
            } else {
                cont[b] = 0.0f;
            }
        }
        if (b == 0) ctrl[12] = (unsigned)(step + 1);
    }
    co = __shfl(co, 0, 64);
    if (step == 0 || co != 0.0f) {
        float4* dst = (float4*)(acc_out + base);
        const f16x4* hi4 = (const f16x4*)(h2hi + base);
        const f16x4* lo4 = (const f16x4*)(h2lo + base);
#pragma unroll
        for (int j = 0; j < 4; ++j) {
            const int i = lane + 64 * j;
            const f16x4 hv = hi4[i];
            const f16x4 lv = lo4[i];
            float4 d = (step == 0) ? (float4){0.f, 0.f, 0.f, 0.f} : dst[i];
            d.x = fmaf(co, (float)hv[0] + (float)lv[0], d.x);
            d.y = fmaf(co, (float)hv[1] + (float)lv[1], d.y);
            d.z = fmaf(co, (float)hv[2] + (float)lv[2], d.z);
            d.w = fmaf(co, (float)hv[3] + (float)lv[3], d.w);
            dst[i] = d;
        }
    }
}

__global__ __launch_bounds__(256) void k_small_init(
    float* __restrict__ halt, float* __restrict__ cont,
    float* __restrict__ ponder_out, unsigned* __restrict__ ctrl)
{
    const int b = blockIdx.x * 256 + threadIdx.x;
    if (b < 4096) { halt[b] = 0.0f; cont[b] = 1.0f; ponder_out[b] = 0.0f; }
    if (b < 16) ctrl[b] = 0u;
}

// flat fp32 -> f16 hi/lo pairs (4096*1024 elements)
__global__ __launch_bounds__(256) void k_split_flat(
    const float* __restrict__ src, f16* __restrict__ hi, f16* __restrict__ lo)
{
    const size_t i = ((size_t)blockIdx.x * 256 + threadIdx.x) * 4;
    const float4 v = *(const float4*)(src + i);
    const f16 s0 = (f16)v.x, s1 = (f16)v.y, s2 = (f16)v.z, s3 = (f16)v.w;
    const f16x4 hv = {s0, s1, s2, s3};
    const f16x4 lw = {(f16)(v.x - (float)s0), (f16)(v.y - (float)s1),
                      (f16)(v.z - (float)s2), (f16)(v.w - (float)s3)};
    *(f16x4*)(hi + i) = hv;
    *(f16x4*)(lo + i) = lw;
}

// Wih1 [4096][1025]: cols 0..1023 -> pairs; col 1024 -> flagcol
__global__ __launch_bounds__(256) void k_split_wih1(
    const float* __restrict__ src, f16* __restrict__ hi, f16* __restrict__ lo,
    float* __restrict__ flagcol)
{
    const int t = blockIdx.x * 256 + threadIdx.x;
    const int row = t >> 8, c4 = (t & 255) << 2;
    const float* s = src + (size_t)row * 1025 + c4;
    const float v0 = s[0], v1 = s[1], v2 = s[2], v3 = s[3];
    const f16 s0 = (f16)v0, s1 = (f16)v1, s2 = (f16)v2, s3 = (f16)v3;
    const f16x4 hv = {s0, s1, s2, s3};
    const f16x4 lw = {(f16)(v0 - (float)s0), (f16)(v1 - (float)s1),
                      (f16)(v2 - (float)s2), (f16)(v3 - (float)s3)};
    const size_t di = (size_t)row * 1024 + c4;
    *(f16x4*)(hi + di) = hv;
    *(f16x4*)(lo + di) = lw;
    if ((t & 255) == 0) flagcol[row] = src[(size_t)row * 1025 + 1024];
}

__global__ __launch_bounds__(256) void k_fin1(
    const f16* __restrict__ h1hi0, const f16* __restrict__ h1hi1,
    const f16* __restrict__ h1lo0, const f16* __restrict__ h1lo1,
    const f16* __restrict__ h2hi0, const f16* __restrict__ h2hi1,
    const f16* __restrict__ h2lo0, const f16* __restrict__ h2lo1,
    const float* __restrict__ c1s, const float* __restrict__ c2s,
    const float* __restrict__ halt, const float* __restrict__ cont,
    const unsigned* __restrict__ ctrl, float* __restrict__ out)
{
    const int par = (int)(ctrl[12] & 1u);
    const f16* h1h = par ? h1hi1 : h1hi0;
    const f16* h1l = par ? h1lo1 : h1lo0;
    const f16* h2h = par ? h2hi1 : h2hi0;
    const f16* h2l = par ? h2lo1 : h2lo0;
    const int b = blockIdx.x;
    const float rem = (cont[b] != 0.0f) ? (1.0f - halt[b]) : 0.0f;
    const int base = b * 1024;
    for (int i = threadIdx.x; i < 1024; i += 256) {
        const float h1v = (float)h1h[base + i] + (float)h1l[base + i];
        const float h2v = (float)h2h[base + i] + (float)h2l[base + i];
        out[O_H1 + base + i] = h1v;
        out[O_C1 + base + i] = c1s[base + i];
        out[O_H2 + base + i] = h2v;
        out[O_C2 + base + i] = c2s[base + i];
        if (rem != 0.0f) out[O_ACC + base + i] += rem * h2v;
    }
}

__global__ __launch_bounds__(256) void k_fin2(
    const float* __restrict__ halt, float* __restrict__ out)
{
    __shared__ float red[256];
    float s = 0.0f;
    for (int i = threadIdx.x; i < 4096; i += 256) s += halt[i];
    red[threadIdx.x] = s;
    __syncthreads();
    for (int w = 128; w > 0; w >>= 1) {
        if (threadIdx.x < w) red[threadIdx.x] += red[threadIdx.x + w];
        __syncthreads();
    }
    if (threadIdx.x == 0) out[O_PCOST] = -0.01f * (red[0] * (1.0f / 4096.0f));
}

extern "C" void kernel_launch(void* const* d_in, const int* in_sizes, int n_in,
                              void* d_out, int out_size, void* d_ws, size_t ws_size,
                              hipStream_t stream) {
    const float* inputs = (const float*)d_in[0];
    const float* W_ih1  = (const float*)d_in[1];
    const float* W_hh1  = (const float*)d_in[2];
    const float* b_ih1  = (const float*)d_in[3];
    const float* b_hh1  = (const float*)d_in[4];
    const float* W_ih2  = (const float*)d_in[5];
    const float* W_hh2  = (const float*)d_in[6];
    const float* b_ih2  = (const float*)d_in[7];
    const float* b_hh2  = (const float*)d_in[8];
    const float* W_halt = (const float*)d_in[9];
    const float* b_halt = (const float*)d_in[10];

    float* out = (float*)d_out;
    float* Z1  = out + O_H1;                  // 64 MB in d_out's dead state region

    char* wsb = (char*)d_ws;
    float* c1s = (float*)(wsb + WS_C1);
    float* c2s = (float*)(wsb + WS_C2);
    f16* h1hi[2] = { (f16*)(wsb + WS_H1HI0), (f16*)(wsb + WS_H1HI1) };
    f16* h1lo[2] = { (f16*)(wsb + WS_H1LO0), (f16*)(wsb + WS_H1LO1) };
    f16* h2hi[2] = { (f16*)(wsb + WS_H2HI0), (f16*)(wsb + WS_H2HI1) };
    f16* h2lo[2] = { (f16*)(wsb + WS_H2LO0), (f16*)(wsb + WS_H2LO1) };
    f16* acthi   = (f16*)(wsb + WS_ACTHI);
    f16* actlo   = (f16*)(wsb + WS_ACTLO);
    float* halt    = (float*)(wsb + WS_MISC);
    float* cont    = halt + 4096;
    float* coef    = cont + 4096;
    float* flagcol = coef + 4096;
    unsigned* ctrl = (unsigned*)(flagcol + 4096);

    // x / W1 pairs live in the step-0-dead h ping-pong set 0 slots
    f16* xhi  = h1hi[0]; f16* xlo  = h1lo[0];
    f16* W1hi = h2hi[0]; f16* W1lo = h2lo[0];

    k_small_init<<<16, 256, 0, stream>>>(halt, cont, out + O_PSTEP, ctrl);

    k_split_wih1<<<4096, 256, 0, stream>>>(W_ih1, W1hi, W1lo, flagcol);
    k_split_flat<<<4096, 256, 0, stream>>>(inputs, xhi, xlo);
    k_z1<<<256, 512, 0, stream>>>(xhi, xlo, W1hi, W1lo, b_ih1, b_hh1, Z1);

    for (int s = 0; s < TSTEPS; ++s) {
        const int wsel = (s & 1) ? 0 : 1;
        const int rsel = 1 - wsel;
        const unsigned* cnt_prev = ctrl + (s > 0 ? s - 1 : 0);

        k_stepA<<<256, 512, 0, stream>>>(Z1, W_hh1, h1hi[rsel], h1lo[rsel],
                                         flagcol, c1s,
                                         h1hi[wsel], h1lo[wsel], acthi, actlo,
                                         cnt_prev, s);
        k_stepB<<<256, 512, 0, stream>>>(acthi, actlo, W_ih2,
                                         h2hi[rsel], h2lo[rsel], W_hh2,
                                         b_ih2, b_hh2, c2s,
                                         h2hi[wsel], h2lo[wsel],
                                         cnt_prev, s);
        k_haltacc<<<1024, 256, 0, stream>>>(h2hi[wsel], h2lo[wsel], W_halt, b_halt,
                                            halt, cont, out + O_PSTEP, ctrl,
                                            out + O_ACC, cnt_prev, s);
    }

    k_fin1<<<4096, 256, 0, stream>>>(h1hi[0], h1hi[1], h1lo[0], h1lo[1],
                                     h2hi[0], h2hi[1], h2lo[0], h2lo[1],
                                     c1s, c2s, halt, cont, ctrl, out);
    k_fin2<<<1, 256, 0, stream>>>(halt, out);
}

// Round 7
// 1572.451 us; speedup vs baseline: 3.1846x; 3.1846x over previous
//
#include <hip/hip_runtime.h>
#include <cstdint>
#include <cstddef>

// ---------------------------------------------------------------------------
// AdaptiveLSTMBlockWrapper — round 7: R6 engine with the register-pressure
// fix (per-ks B staging, grouped A-frag reads, collapsed address arrays,
// launch_bounds(512,2)). A-only LDS, r3/r6-proven 0-conflict geometry
// (128B rows, 8x16B slots, slot^(row&7)); B global->reg from L2-resident
// slab; 1 barrier + cheap vmcnt(0)s per K-step. 3-product split-f16 MFMA.
//
// Engine: 256x256 block, 8 waves (2M x 4N), wave tile 128 rows x 64 vcols.
// LDS: 2 buffers x (Ahi 32KB + Alo 32KB) = 128KB. 16 K-steps of K=64.
// Per kt: [issueA(kt+1)->bn] then per ks in {0,1}:
//   [cvt P -> bh/bl] [load next-ks B -> P] [4x {2 A-frag reads + 24 MFMA}]
//   [vmcnt(0): drains ~900-cyc-old loads, ~free]
// then [barrier]. Register budget ~240 < 256.
// ---------------------------------------------------------------------------

typedef _Float16 f16;
typedef f16   f16x8 __attribute__((ext_vector_type(8)));
typedef f16   f16x4 __attribute__((ext_vector_type(4)));
typedef float f32x4 __attribute__((ext_vector_type(4)));

#define TSTEPS 12

// d_out float offsets
#define O_ACC   0u
#define O_H1    4194304u
#define O_C1    8388608u
#define O_H2    12582912u
#define O_C2    16777216u
#define O_PCOST 20971520u
#define O_PSTEP 20971521u

// ws byte offsets
#define WS_C1    (size_t)(0u)
#define WS_C2    ((size_t)16u<<20)
#define WS_H1HI0 ((size_t)32u<<20)
#define WS_H1HI1 ((size_t)40u<<20)
#define WS_H1LO0 ((size_t)48u<<20)
#define WS_H1LO1 ((size_t)56u<<20)
#define WS_H2HI0 ((size_t)64u<<20)
#define WS_H2HI1 ((size_t)72u<<20)
#define WS_H2LO0 ((size_t)80u<<20)
#define WS_H2LO1 ((size_t)88u<<20)
#define WS_ACTHI ((size_t)96u<<20)
#define WS_ACTLO ((size_t)104u<<20)
#define WS_MISC  ((size_t)112u<<20)

// LDS: 2 buffers; within a buffer: Ahi at 0 (32KB), Alo at 32768 (32KB)
#define SEC_ALO 32768
#define BUFSZ   65536

__device__ __forceinline__ float sigmoidf_(float x) { return 1.0f / (1.0f + expf(-x)); }

__device__ __forceinline__ void glds16(const void* g, void* l) {
    __builtin_amdgcn_global_load_lds(
        (const __attribute__((address_space(1))) unsigned int*)g,
        (__attribute__((address_space(3))) unsigned int*)l, 16, 0, 0);
}

// Grid: 256 blocks (16 m x 16 hc). XCD-major over hc: 2MB weight slab/XCD.
__device__ __forceinline__ void block_tile(int& m0, int& hc0) {
    const int bid = blockIdx.x;
    const int lid = (bid & 7) * 32 + (bid >> 3);
    m0  = (lid & 15) * 256;
    hc0 = (lid >> 4) * 64;
}

// ---------------------------------------------------------------------------
// acc += A(256 rows x 1024) * B(256 vcols x 1024)^T, split-f16 3-product.
// A: pre-split f16 pairs, glds into LDS (128B rows, 8x16B slots, invariant:
//    slot s of row r holds k-chunk s^(r&7)) — r3/r6-proven zero-conflict.
// B: straight to registers per-ks. B_PAIR: f16 hi/lo pairs; else fp32 +
//    split on the fly. wrow = nf*1024 + hc0 + wnb*16 + l15; lane k-chunk lk*8.
// ---------------------------------------------------------------------------
template<bool B_PAIR>
__device__ __forceinline__ void passK64(
    const f16* __restrict__ Ahi, const f16* __restrict__ Alo,
    const f16* __restrict__ Bhi, const f16* __restrict__ Blo,
    const float* __restrict__ Bf32,
    int m0, int hc0, f32x4 (&acc)[8][4], char* sm)
{
    const int tid = threadIdx.x, lane = tid & 63, wid = tid >> 6;
    const int wm  = (wid >> 2) * 128;
    const int wnb = wid & 3;
    const int l15 = lane & 15, lk = lane >> 4;

    // A fragment read offsets (per mf)
    int rbase[8], rx[8];
#pragma unroll
    for (int mf = 0; mf < 8; ++mf) {
        const int row = wm + mf * 16 + l15;
        rbase[mf] = row * 128;
        rx[mf]    = row & 7;
    }

    // A glds: 8 ops/wave. sec = wid>>2 (wave-uniform), j = (wid&3)*8 + i.
    // lane l: row-in-chunk = l>>3, slot = l&7, global k-chunk = (l&7)^(l>>3).
    const int secA = wid >> 2;
    const int j0   = (wid & 3) * 8;
    const int rl = lane >> 3, sl = lane & 7;
    const f16* gaBase = (secA ? Alo : Ahi)
                        + (size_t)(m0 + j0 * 8 + rl) * 1024 + ((sl ^ rl) << 3);
    const int albase0 = secA * SEC_ALO + j0 * 1024;

    // B base (single pointer; nf offsets are unroll-time constants)
    const int wrow0 = hc0 + wnb * 16 + l15;
    const float* pB32 = nullptr;
    const f16* pBh = nullptr;
    const f16* pBl = nullptr;
    if constexpr (B_PAIR) {
        pBh = Bhi + (size_t)wrow0 * 1024 + lk * 8;
        pBl = Blo + (size_t)wrow0 * 1024 + lk * 8;
    } else {
        pB32 = Bf32 + (size_t)wrow0 * 1024 + lk * 8;
    }

    // B raw staging for ONE ks (32 VGPR)
    float4 P[8];     // fp32 mode
    int4   Ph[4], Pl[4];  // pair mode

    auto issueA = [&](int kt, char* buf) {
#pragma unroll
        for (int i = 0; i < 8; ++i)
            glds16(gaBase + (size_t)i * 8192 + kt * 64, buf + albase0 + i * 1024);
    };
    auto loadB = [&](int kt, int ks) {
#pragma unroll
        for (int nf = 0; nf < 4; ++nf) {
            if constexpr (B_PAIR) {
                Ph[nf] = *(const int4*)(pBh + (size_t)nf * 1048576 + kt * 64 + ks * 32);
                Pl[nf] = *(const int4*)(pBl + (size_t)nf * 1048576 + kt * 64 + ks * 32);
            } else {
                const float* p = pB32 + (size_t)nf * 1048576 + kt * 64 + ks * 32;
                P[2 * nf]     = *(const float4*)(p);
                P[2 * nf + 1] = *(const float4*)(p + 4);
            }
        }
    };

    // ---- prologue ----
    issueA(0, sm);
    loadB(0, 0);
    asm volatile("s_waitcnt vmcnt(0)" ::: "memory");
    __builtin_amdgcn_s_barrier();
    asm volatile("" ::: "memory");

#pragma unroll 1
    for (int kt = 0; kt < 16; ++kt) {
        char* bc = sm + (kt & 1) * BUFSZ;
        char* bn = sm + ((kt + 1) & 1) * BUFSZ;
        if (kt < 15) issueA(kt + 1, bn);

#pragma unroll
        for (int ks = 0; ks < 2; ++ks) {
            // cvt P (retired) -> bh/bl fragments
            f16x8 bh[4], bl[4];
#pragma unroll
            for (int nf = 0; nf < 4; ++nf) {
                if constexpr (B_PAIR) {
                    bh[nf] = *(const f16x8*)&Ph[nf];
                    bl[nf] = *(const f16x8*)&Pl[nf];
                } else {
                    const float* f0 = (const float*)&P[2 * nf];
                    const float* f1 = (const float*)&P[2 * nf + 1];
                    f16x8 h, l;
#pragma unroll
                    for (int j = 0; j < 4; ++j) {
                        const f16 a = (f16)f0[j];
                        h[j] = a; l[j] = (f16)(f0[j] - (float)a);
                        const f16 b = (f16)f1[j];
                        h[4 + j] = b; l[4 + j] = (f16)(f1[j] - (float)b);
                    }
                    bh[nf] = h; bl[nf] = l;
                }
            }
            // issue next-ks B load (covered by the MFMA cluster below)
            const int nkt = ks ? kt + 1 : kt;
            if (nkt < 16) loadB(nkt, ks ^ 1);

            // A frags in groups of 2 mf + 24 MFMAs per group
#pragma unroll
            for (int mg = 0; mg < 4; ++mg) {
                const int o0 = rbase[2 * mg]     + ((((ks << 2) | lk) ^ rx[2 * mg])     << 4);
                const int o1 = rbase[2 * mg + 1] + ((((ks << 2) | lk) ^ rx[2 * mg + 1]) << 4);
                const f16x8 ah0 = *(const f16x8*)(bc + o0);
                const f16x8 al0 = *(const f16x8*)(bc + SEC_ALO + o0);
                const f16x8 ah1 = *(const f16x8*)(bc + o1);
                const f16x8 al1 = *(const f16x8*)(bc + SEC_ALO + o1);
#pragma unroll
                for (int nf = 0; nf < 4; ++nf) {
                    acc[2 * mg][nf]     = __builtin_amdgcn_mfma_f32_16x16x32_f16(ah0, bh[nf], acc[2 * mg][nf], 0, 0, 0);
                    acc[2 * mg][nf]     = __builtin_amdgcn_mfma_f32_16x16x32_f16(ah0, bl[nf], acc[2 * mg][nf], 0, 0, 0);
                    acc[2 * mg][nf]     = __builtin_amdgcn_mfma_f32_16x16x32_f16(al0, bh[nf], acc[2 * mg][nf], 0, 0, 0);
                    acc[2 * mg + 1][nf] = __builtin_amdgcn_mfma_f32_16x16x32_f16(ah1, bh[nf], acc[2 * mg + 1][nf], 0, 0, 0);
                    acc[2 * mg + 1][nf] = __builtin_amdgcn_mfma_f32_16x16x32_f16(ah1, bl[nf], acc[2 * mg + 1][nf], 0, 0, 0);
                    acc[2 * mg + 1][nf] = __builtin_amdgcn_mfma_f32_16x16x32_f16(al1, bh[nf], acc[2 * mg + 1][nf], 0, 0, 0);
                }
            }
            // drain: loads here are ~1 MFMA-cluster old -> near-free
            asm volatile("s_waitcnt vmcnt(0)" ::: "memory");
        }
        if (kt < 15) {
            __builtin_amdgcn_s_barrier();
            asm volatile("" ::: "memory");
        }
    }
}

// Z1 = x@W1^T + b_ih1 + b_hh1 (x pairs staged; W1 pairs direct-to-reg)
__global__ __launch_bounds__(512, 2) void k_z1(
    const f16* __restrict__ xhi, const f16* __restrict__ xlo,
    const f16* __restrict__ W1hi, const f16* __restrict__ W1lo,
    const float* __restrict__ bih1, const float* __restrict__ bhh1,
    float* __restrict__ Z1)
{
    __shared__ __align__(16) char sm[2 * BUFSZ];
    int m0, hc0; block_tile(m0, hc0);
    f32x4 acc[8][4];
#pragma unroll
    for (int a = 0; a < 8; ++a)
#pragma unroll
        for (int b = 0; b < 4; ++b) acc[a][b] = (f32x4){0.f, 0.f, 0.f, 0.f};
    passK64<true>(xhi, xlo, W1hi, W1lo, nullptr, m0, hc0, acc, sm);

    const int tid = threadIdx.x, lane = tid & 63, wid = tid >> 6;
    const int wm = (wid >> 2) * 128, wnb = wid & 3, l15 = lane & 15, lk = lane >> 4;
    const int hc = hc0 + wnb * 16 + l15;
#pragma unroll
    for (int mf = 0; mf < 8; ++mf)
#pragma unroll
        for (int r = 0; r < 4; ++r) {
            const int row = m0 + wm + mf * 16 + lk * 4 + r;
#pragma unroll
            for (int g = 0; g < 4; ++g) {
                const int R = g * 1024 + hc;
                Z1[(size_t)row * 4096 + R] = acc[mf][g][r] + bih1[R] + bhh1[R];
            }
        }
}

// Layer-1 cell: gates = Z1 (+flag col @step0) + h1@Whh1^T
__global__ __launch_bounds__(512, 2) void k_stepA(
    const float* __restrict__ Z1, const float* __restrict__ Whh1,
    const f16* __restrict__ h1hi_in, const f16* __restrict__ h1lo_in,
    const float* __restrict__ flagcol, float* __restrict__ c1,
    f16* __restrict__ h1hi_out, f16* __restrict__ h1lo_out,
    f16* __restrict__ acthi, f16* __restrict__ actlo,
    const unsigned* __restrict__ cnt_prev, int step)
{
    if (step > 0 && cnt_prev[0] == 0u) return;
    __shared__ __align__(16) char sm[2 * BUFSZ];
    int m0, hc0; block_tile(m0, hc0);
    f32x4 acc[8][4];
#pragma unroll
    for (int a = 0; a < 8; ++a)
#pragma unroll
        for (int b = 0; b < 4; ++b) acc[a][b] = (f32x4){0.f, 0.f, 0.f, 0.f};
    if (step > 0)
        passK64<false>(h1hi_in, h1lo_in, nullptr, nullptr, Whh1, m0, hc0, acc, sm);

    const int tid = threadIdx.x, lane = tid & 63, wid = tid >> 6;
    const int wm = (wid >> 2) * 128, wnb = wid & 3, l15 = lane & 15, lk = lane >> 4;
    const int hc = hc0 + wnb * 16 + l15;
#pragma unroll
    for (int mf = 0; mf < 8; ++mf)
#pragma unroll
        for (int r = 0; r < 4; ++r) {
            const int row = m0 + wm + mf * 16 + lk * 4 + r;
            float p[4];
#pragma unroll
            for (int g = 0; g < 4; ++g) {
                const int R = g * 1024 + hc;
                p[g] = acc[mf][g][r] + Z1[(size_t)row * 4096 + R];
                if (step == 0) p[g] += flagcol[R];
            }
            const float ig = sigmoidf_(p[0]);
            const float fg = sigmoidf_(p[1]);
            const float gg = tanhf(p[2]);
            const float og = sigmoidf_(p[3]);
            const int idx = row * 1024 + hc;
            const float cold = (step == 0) ? 0.0f : c1[idx];
            const float cn = fg * cold + ig * gg;
            c1[idx] = cn;
            const float h = og * tanhf(cn);
            const f16 hh = (f16)h;
            const f16 hl = (f16)(h - (float)hh);
            h1hi_out[idx] = hh; h1lo_out[idx] = hl;
            const bool pos = h > 0.0f;
            acthi[idx] = pos ? hh : (f16)0.0f;
            actlo[idx] = pos ? hl : (f16)0.0f;
        }
}

// Layer-2 cell: gates = b2 + act@Wih2^T + h2@Whh2^T
__global__ __launch_bounds__(512, 2) void k_stepB(
    const f16* __restrict__ acthi, const f16* __restrict__ actlo,
    const float* __restrict__ Wih2,
    const f16* __restrict__ h2hi_in, const f16* __restrict__ h2lo_in,
    const float* __restrict__ Whh2,
    const float* __restrict__ bih2, const float* __restrict__ bhh2,
    float* __restrict__ c2, f16* __restrict__ h2hi_out, f16* __restrict__ h2lo_out,
    const unsigned* __restrict__ cnt_prev, int step)
{
    if (step > 0 && cnt_prev[0] == 0u) return;
    __shared__ __align__(16) char sm[2 * BUFSZ];
    int m0, hc0; block_tile(m0, hc0);
    f32x4 acc[8][4];
#pragma unroll
    for (int a = 0; a < 8; ++a)
#pragma unroll
        for (int b = 0; b < 4; ++b) acc[a][b] = (f32x4){0.f, 0.f, 0.f, 0.f};
    passK64<false>(acthi, actlo, nullptr, nullptr, Wih2, m0, hc0, acc, sm);
    if (step > 0)
        passK64<false>(h2hi_in, h2lo_in, nullptr, nullptr, Whh2, m0, hc0, acc, sm);

    const int tid = threadIdx.x, lane = tid & 63, wid = tid >> 6;
    const int wm = (wid >> 2) * 128, wnb = wid & 3, l15 = lane & 15, lk = lane >> 4;
    const int hc = hc0 + wnb * 16 + l15;
#pragma unroll
    for (int mf = 0; mf < 8; ++mf)
#pragma unroll
        for (int r = 0; r < 4; ++r) {
            const int row = m0 + wm + mf * 16 + lk * 4 + r;
            float p[4];
#pragma unroll
            for (int g = 0; g < 4; ++g) {
                const int R = g * 1024 + hc;
                p[g] = acc[mf][g][r] + bih2[R] + bhh2[R];
            }
            const float ig = sigmoidf_(p[0]);
            const float fg = sigmoidf_(p[1]);
            const float gg = tanhf(p[2]);
            const float og = sigmoidf_(p[3]);
            const int idx = row * 1024 + hc;
            const float cold = (step == 0) ? 0.0f : c2[idx];
            const float cn = fg * cold + ig * gg;
            c2[idx] = cn;
            const float h = og * tanhf(cn);
            const f16 hh = (f16)h;
            h2hi_out[idx] = hh;
            h2lo_out[idx] = (f16)(h - (float)hh);
        }
}

// Merged halting state machine + acc_out accumulate (one wave per row).
__global__ __launch_bounds__(256) void k_haltacc(
    const f16* __restrict__ h2hi, const f16* __restrict__ h2lo,
    const float* __restrict__ Whalt, const float* __restrict__ bhalt,
    float* __restrict__ halt, float* __restrict__ cont,
    float* __restrict__ ponder_out, unsigned* __restrict__ ctrl,
    float* __restrict__ acc_out,
    const unsigned* __restrict__ cnt_prev, int step)
{
    if (step > 0 && cnt_prev[0] == 0u) return;
    const int lane = threadIdx.x & 63;
    const int b = blockIdx.x * 4 + (threadIdx.x >> 6);
    const size_t base = (size_t)b * 1024;
    float sum = 0.0f;
    for (int k = lane; k < 1024; k += 64)
        sum += ((float)h2hi[base + k] + (float)h2lo[base + k]) * Whalt[k];
#pragma unroll
    for (int off = 32; off > 0; off >>= 1) sum += __shfl_down(sum, off, 64);
    float co = 0.0f;
    if (lane == 0) {
        const float sh = sigmoidf_(sum + bhalt[0]);
        if (cont[b] != 0.0f) {
            const float hn = halt[b] + sh;
            const bool ending = hn > 0.99f;
            co = sh + (ending ? (1.0f - hn) : 0.0f);
            halt[b] = hn;
            if (!ending) {
                ponder_out[b] += 1.0f;
                atomicAdd(&ctrl[step], 1u);
            } else {
                cont[b] = 0.0f;
            }
        }
        if (b == 0) ctrl[12] = (unsigned)(step + 1);
    }
    co = __shfl(co, 0, 64);
    if (step == 0 || co != 0.0f) {
        float4* dst = (float4*)(acc_out + base);
        const f16x4* hi4 = (const f16x4*)(h2hi + base);
        const f16x4* lo4 = (const f16x4*)(h2lo + base);
#pragma unroll
        for (int j = 0; j < 4; ++j) {
            const int i = lane + 64 * j;
            const f16x4 hv = hi4[i];
            const f16x4 lv = lo4[i];
            float4 d = (step == 0) ? (float4){0.f, 0.f, 0.f, 0.f} : dst[i];
            d.x = fmaf(co, (float)hv[0] + (float)lv[0], d.x);
            d.y = fmaf(co, (float)hv[1] + (float)lv[1], d.y);
            d.z = fmaf(co, (float)hv[2] + (float)lv[2], d.z);
            d.w = fmaf(co, (float)hv[3] + (float)lv[3], d.w);
            dst[i] = d;
        }
    }
}

__global__ __launch_bounds__(256) void k_small_init(
    float* __restrict__ halt, float* __restrict__ cont,
    float* __restrict__ ponder_out, unsigned* __restrict__ ctrl)
{
    const int b = blockIdx.x * 256 + threadIdx.x;
    if (b < 4096) { halt[b] = 0.0f; cont[b] = 1.0f; ponder_out[b] = 0.0f; }
    if (b < 16) ctrl[b] = 0u;
}

// flat fp32 -> f16 hi/lo pairs (4096*1024 elements)
__global__ __launch_bounds__(256) void k_split_flat(
    const float* __restrict__ src, f16* __restrict__ hi, f16* __restrict__ lo)
{
    const size_t i = ((size_t)blockIdx.x * 256 + threadIdx.x) * 4;
    const float4 v = *(const float4*)(src + i);
    const f16 s0 = (f16)v.x, s1 = (f16)v.y, s2 = (f16)v.z, s3 = (f16)v.w;
    const f16x4 hv = {s0, s1, s2, s3};
    const f16x4 lw = {(f16)(v.x - (float)s0), (f16)(v.y - (float)s1),
                      (f16)(v.z - (float)s2), (f16)(v.w - (float)s3)};
    *(f16x4*)(hi + i) = hv;
    *(f16x4*)(lo + i) = lw;
}

// Wih1 [4096][1025]: cols 0..1023 -> pairs; col 1024 -> flagcol
__global__ __launch_bounds__(256) void k_split_wih1(
    const float* __restrict__ src, f16* __restrict__ hi, f16* __restrict__ lo,
    float* __restrict__ flagcol)
{
    const int t = blockIdx.x * 256 + threadIdx.x;
    const int row = t >> 8, c4 = (t & 255) << 2;
    const float* s = src + (size_t)row * 1025 + c4;
    const float v0 = s[0], v1 = s[1], v2 = s[2], v3 = s[3];
    const f16 s0 = (f16)v0, s1 = (f16)v1, s2 = (f16)v2, s3 = (f16)v3;
    const f16x4 hv = {s0, s1, s2, s3};
    const f16x4 lw = {(f16)(v0 - (float)s0), (f16)(v1 - (float)s1),
                      (f16)(v2 - (float)s2), (f16)(v3 - (float)s3)};
    const size_t di = (size_t)row * 1024 + c4;
    *(f16x4*)(hi + di) = hv;
    *(f16x4*)(lo + di) = lw;
    if ((t & 255) == 0) flagcol[row] = src[(size_t)row * 1025 + 1024];
}

__global__ __launch_bounds__(256) void k_fin1(
    const f16* __restrict__ h1hi0, const f16* __restrict__ h1hi1,
    const f16* __restrict__ h1lo0, const f16* __restrict__ h1lo1,
    const f16* __restrict__ h2hi0, const f16* __restrict__ h2hi1,
    const f16* __restrict__ h2lo0, const f16* __restrict__ h2lo1,
    const float* __restrict__ c1s, const float* __restrict__ c2s,
    const float* __restrict__ halt, const float* __restrict__ cont,
    const unsigned* __restrict__ ctrl, float* __restrict__ out)
{
    const int par = (int)(ctrl[12] & 1u);
    const f16* h1h = par ? h1hi1 : h1hi0;
    const f16* h1l = par ? h1lo1 : h1lo0;
    const f16* h2h = par ? h2hi1 : h2hi0;
    const f16* h2l = par ? h2lo1 : h2lo0;
    const int b = blockIdx.x;
    const float rem = (cont[b] != 0.0f) ? (1.0f - halt[b]) : 0.0f;
    const int base = b * 1024;
    for (int i = threadIdx.x; i < 1024; i += 256) {
        const float h1v = (float)h1h[base + i] + (float)h1l[base + i];
        const float h2v = (float)h2h[base + i] + (float)h2l[base + i];
        out[O_H1 + base + i] = h1v;
        out[O_C1 + base + i] = c1s[base + i];
        out[O_H2 + base + i] = h2v;
        out[O_C2 + base + i] = c2s[base + i];
        if (rem != 0.0f) out[O_ACC + base + i] += rem * h2v;
    }
}

__global__ __launch_bounds__(256) void k_fin2(
    const float* __restrict__ halt, float* __restrict__ out)
{
    __shared__ float red[256];
    float s = 0.0f;
    for (int i = threadIdx.x; i < 4096; i += 256) s += halt[i];
    red[threadIdx.x] = s;
    __syncthreads();
    for (int w = 128; w > 0; w >>= 1) {
        if (threadIdx.x < w) red[threadIdx.x] += red[threadIdx.x + w];
        __syncthreads();
    }
    if (threadIdx.x == 0) out[O_PCOST] = -0.01f * (red[0] * (1.0f / 4096.0f));
}

extern "C" void kernel_launch(void* const* d_in, const int* in_sizes, int n_in,
                              void* d_out, int out_size, void* d_ws, size_t ws_size,
                              hipStream_t stream) {
    const float* inputs = (const float*)d_in[0];
    const float* W_ih1  = (const float*)d_in[1];
    const float* W_hh1  = (const float*)d_in[2];
    const float* b_ih1  = (const float*)d_in[3];
    const float* b_hh1  = (const float*)d_in[4];
    const float* W_ih2  = (const float*)d_in[5];
    const float* W_hh2  = (const float*)d_in[6];
    const float* b_ih2  = (const float*)d_in[7];
    const float* b_hh2  = (const float*)d_in[8];
    const float* W_halt = (const float*)d_in[9];
    const float* b_halt = (const float*)d_in[10];

    float* out = (float*)d_out;
    float* Z1  = out + O_H1;                  // 64 MB in d_out's dead state region

    char* wsb = (char*)d_ws;
    float* c1s = (float*)(wsb + WS_C1);
    float* c2s = (float*)(wsb + WS_C2);
    f16* h1hi[2] = { (f16*)(wsb + WS_H1HI0), (f16*)(wsb + WS_H1HI1) };
    f16* h1lo[2] = { (f16*)(wsb + WS_H1LO0), (f16*)(wsb + WS_H1LO1) };
    f16* h2hi[2] = { (f16*)(wsb + WS_H2HI0), (f16*)(wsb + WS_H2HI1) };
    f16* h2lo[2] = { (f16*)(wsb + WS_H2LO0), (f16*)(wsb + WS_H2LO1) };
    f16* acthi   = (f16*)(wsb + WS_ACTHI);
    f16* actlo   = (f16*)(wsb + WS_ACTLO);
    float* halt    = (float*)(wsb + WS_MISC);
    float* cont    = halt + 4096;
    float* coef    = cont + 4096;
    float* flagcol = coef + 4096;
    unsigned* ctrl = (unsigned*)(flagcol + 4096);

    // x / W1 pairs live in the step-0-dead h ping-pong set 0 slots
    f16* xhi  = h1hi[0]; f16* xlo  = h1lo[0];
    f16* W1hi = h2hi[0]; f16* W1lo = h2lo[0];

    k_small_init<<<16, 256, 0, stream>>>(halt, cont, out + O_PSTEP, ctrl);

    k_split_wih1<<<4096, 256, 0, stream>>>(W_ih1, W1hi, W1lo, flagcol);
    k_split_flat<<<4096, 256, 0, stream>>>(inputs, xhi, xlo);
    k_z1<<<256, 512, 0, stream>>>(xhi, xlo, W1hi, W1lo, b_ih1, b_hh1, Z1);

    for (int s = 0; s < TSTEPS; ++s) {
        const int wsel = (s & 1) ? 0 : 1;
        const int rsel = 1 - wsel;
        const unsigned* cnt_prev = ctrl + (s > 0 ? s - 1 : 0);

        k_stepA<<<256, 512, 0, stream>>>(Z1, W_hh1, h1hi[rsel], h1lo[rsel],
                                         flagcol, c1s,
                                         h1hi[wsel], h1lo[wsel], acthi, actlo,
                                         cnt_prev, s);
        k_stepB<<<256, 512, 0, stream>>>(acthi, actlo, W_ih2,
                                         h2hi[rsel], h2lo[rsel], W_hh2,
                                         b_ih2, b_hh2, c2s,
                                         h2hi[wsel], h2lo[wsel],
                                         cnt_prev, s);
        k_haltacc<<<1024, 256, 0, stream>>>(h2hi[wsel], h2lo[wsel], W_halt, b_halt,
                                            halt, cont, out + O_PSTEP, ctrl,
                                            out + O_ACC, cnt_prev, s);
    }

    k_fin1<<<4096, 256, 0, stream>>>(h1hi[0], h1hi[1], h1lo[0], h1lo[1],
                                     h2hi[0], h2hi[1], h2lo[0], h2lo[1],
                                     c1s, c2s, halt, cont, ctrl, out);
    k_fin2<<<1, 256, 0, stream>>>(halt, out);
}

// Round 8
// 1493.590 us; speedup vs baseline: 3.3528x; 1.0528x over previous
//
#include <hip/hip_runtime.h>
#include <cstdint>
#include <cstddef>

// ---------------------------------------------------------------------------
// AdaptiveLSTMBlockWrapper — round 8: r7 engine + product-major MFMA ordering
// (dependent-chain distance 3 -> 8) + setprio around MFMA sweeps.
// A-only LDS (r3/r6/r7-proven 0-conflict geometry: 128B rows, 8x16B slots,
// slot^(row&7)); B global->reg from L2-resident slab; 1 barrier/K-step.
// fp32 GEMM = 3-product split-f16 MFMA (Ah*Bh + Ah*Bl + Al*Bh).
//
// Engine: 256x256 block, 8 waves (2M x 4N), wave tile 128 rows x 64 vcols.
// LDS: 2 buffers x (Ahi 32KB + Alo 32KB) = 128KB. 16 K-steps of K=64.
// ---------------------------------------------------------------------------

typedef _Float16 f16;
typedef f16   f16x8 __attribute__((ext_vector_type(8)));
typedef f16   f16x4 __attribute__((ext_vector_type(4)));
typedef float f32x4 __attribute__((ext_vector_type(4)));

#define TSTEPS 12

// d_out float offsets
#define O_ACC   0u
#define O_H1    4194304u
#define O_C1    8388608u
#define O_H2    12582912u
#define O_C2    16777216u
#define O_PCOST 20971520u
#define O_PSTEP 20971521u

// ws byte offsets
#define WS_C1    (size_t)(0u)
#define WS_C2    ((size_t)16u<<20)
#define WS_H1HI0 ((size_t)32u<<20)
#define WS_H1HI1 ((size_t)40u<<20)
#define WS_H1LO0 ((size_t)48u<<20)
#define WS_H1LO1 ((size_t)56u<<20)
#define WS_H2HI0 ((size_t)64u<<20)
#define WS_H2HI1 ((size_t)72u<<20)
#define WS_H2LO0 ((size_t)80u<<20)
#define WS_H2LO1 ((size_t)88u<<20)
#define WS_ACTHI ((size_t)96u<<20)
#define WS_ACTLO ((size_t)104u<<20)
#define WS_MISC  ((size_t)112u<<20)

// LDS: 2 buffers; within a buffer: Ahi at 0 (32KB), Alo at 32768 (32KB)
#define SEC_ALO 32768
#define BUFSZ   65536

__device__ __forceinline__ float sigmoidf_(float x) { return 1.0f / (1.0f + expf(-x)); }

__device__ __forceinline__ void glds16(const void* g, void* l) {
    __builtin_amdgcn_global_load_lds(
        (const __attribute__((address_space(1))) unsigned int*)g,
        (__attribute__((address_space(3))) unsigned int*)l, 16, 0, 0);
}

// Grid: 256 blocks (16 m x 16 hc). XCD-major over hc: 2MB weight slab/XCD.
__device__ __forceinline__ void block_tile(int& m0, int& hc0) {
    const int bid = blockIdx.x;
    const int lid = (bid & 7) * 32 + (bid >> 3);
    m0  = (lid & 15) * 256;
    hc0 = (lid >> 4) * 64;
}

// ---------------------------------------------------------------------------
// acc += A(256 rows x 1024) * B(256 vcols x 1024)^T, split-f16 3-product.
// A: pre-split f16 pairs, glds into LDS (128B rows, 8x16B slots, invariant:
//    slot s of row r holds k-chunk s^(r&7)) — proven zero-conflict.
// B: straight to registers per-ks. B_PAIR: f16 hi/lo pairs; else fp32 +
//    split on the fly. wrow = nf*1024 + hc0 + wnb*16 + l15; lane k-chunk lk*8.
// MFMA emission is PRODUCT-MAJOR: three sweeps over 8 independent (mf,nf)
// accumulators -> dependent-acc reuse distance 8 (was 3).
// ---------------------------------------------------------------------------
template<bool B_PAIR>
__device__ __forceinline__ void passK64(
    const f16* __restrict__ Ahi, const f16* __restrict__ Alo,
    const f16* __restrict__ Bhi, const f16* __restrict__ Blo,
    const float* __restrict__ Bf32,
    int m0, int hc0, f32x4 (&acc)[8][4], char* sm)
{
    const int tid = threadIdx.x, lane = tid & 63, wid = tid >> 6;
    const int wm  = (wid >> 2) * 128;
    const int wnb = wid & 3;
    const int l15 = lane & 15, lk = lane >> 4;

    // A fragment read offsets (per mf)
    int rbase[8], rx[8];
#pragma unroll
    for (int mf = 0; mf < 8; ++mf) {
        const int row = wm + mf * 16 + l15;
        rbase[mf] = row * 128;
        rx[mf]    = row & 7;
    }

    // A glds: 8 ops/wave. sec = wid>>2 (wave-uniform), j = (wid&3)*8 + i.
    // lane l: row-in-chunk = l>>3, slot = l&7, global k-chunk = (l&7)^(l>>3).
    const int secA = wid >> 2;
    const int j0   = (wid & 3) * 8;
    const int rl = lane >> 3, sl = lane & 7;
    const f16* gaBase = (secA ? Alo : Ahi)
                        + (size_t)(m0 + j0 * 8 + rl) * 1024 + ((sl ^ rl) << 3);
    const int albase0 = secA * SEC_ALO + j0 * 1024;

    // B base (single pointer; nf offsets are unroll-time constants)
    const int wrow0 = hc0 + wnb * 16 + l15;
    const float* pB32 = nullptr;
    const f16* pBh = nullptr;
    const f16* pBl = nullptr;
    if constexpr (B_PAIR) {
        pBh = Bhi + (size_t)wrow0 * 1024 + lk * 8;
        pBl = Blo + (size_t)wrow0 * 1024 + lk * 8;
    } else {
        pB32 = Bf32 + (size_t)wrow0 * 1024 + lk * 8;
    }

    // B raw staging for ONE ks (32 VGPR)
    float4 P[8];     // fp32 mode
    int4   Ph[4], Pl[4];  // pair mode

    auto issueA = [&](int kt, char* buf) {
#pragma unroll
        for (int i = 0; i < 8; ++i)
            glds16(gaBase + (size_t)i * 8192 + kt * 64, buf + albase0 + i * 1024);
    };
    auto loadB = [&](int kt, int ks) {
#pragma unroll
        for (int nf = 0; nf < 4; ++nf) {
            if constexpr (B_PAIR) {
                Ph[nf] = *(const int4*)(pBh + (size_t)nf * 1048576 + kt * 64 + ks * 32);
                Pl[nf] = *(const int4*)(pBl + (size_t)nf * 1048576 + kt * 64 + ks * 32);
            } else {
                const float* p = pB32 + (size_t)nf * 1048576 + kt * 64 + ks * 32;
                P[2 * nf]     = *(const float4*)(p);
                P[2 * nf + 1] = *(const float4*)(p + 4);
            }
        }
    };

    // ---- prologue ----
    issueA(0, sm);
    loadB(0, 0);
    asm volatile("s_waitcnt vmcnt(0)" ::: "memory");
    __builtin_amdgcn_s_barrier();
    asm volatile("" ::: "memory");

#pragma unroll 1
    for (int kt = 0; kt < 16; ++kt) {
        char* bc = sm + (kt & 1) * BUFSZ;
        char* bn = sm + ((kt + 1) & 1) * BUFSZ;
        if (kt < 15) issueA(kt + 1, bn);

#pragma unroll
        for (int ks = 0; ks < 2; ++ks) {
            // cvt P (retired) -> bh/bl fragments
            f16x8 bh[4], bl[4];
#pragma unroll
            for (int nf = 0; nf < 4; ++nf) {
                if constexpr (B_PAIR) {
                    bh[nf] = *(const f16x8*)&Ph[nf];
                    bl[nf] = *(const f16x8*)&Pl[nf];
                } else {
                    const float* f0 = (const float*)&P[2 * nf];
                    const float* f1 = (const float*)&P[2 * nf + 1];
                    f16x8 h, l;
#pragma unroll
                    for (int j = 0; j < 4; ++j) {
                        const f16 a = (f16)f0[j];
                        h[j] = a; l[j] = (f16)(f0[j] - (float)a);
                        const f16 b = (f16)f1[j];
                        h[4 + j] = b; l[4 + j] = (f16)(f1[j] - (float)b);
                    }
                    bh[nf] = h; bl[nf] = l;
                }
            }
            // issue next-ks B load (covered by the MFMA clusters below)
            const int nkt = ks ? kt + 1 : kt;
            if (nkt < 16) loadB(nkt, ks ^ 1);

            // A frags in groups of 2 mf; PRODUCT-MAJOR sweeps (8 indep accs)
#pragma unroll
            for (int mg = 0; mg < 4; ++mg) {
                const int o0 = rbase[2 * mg]     + ((((ks << 2) | lk) ^ rx[2 * mg])     << 4);
                const int o1 = rbase[2 * mg + 1] + ((((ks << 2) | lk) ^ rx[2 * mg + 1]) << 4);
                const f16x8 ah0 = *(const f16x8*)(bc + o0);
                const f16x8 al0 = *(const f16x8*)(bc + SEC_ALO + o0);
                const f16x8 ah1 = *(const f16x8*)(bc + o1);
                const f16x8 al1 = *(const f16x8*)(bc + SEC_ALO + o1);
                __builtin_amdgcn_s_setprio(1);
#pragma unroll
                for (int nf = 0; nf < 4; ++nf) {
                    acc[2 * mg][nf]     = __builtin_amdgcn_mfma_f32_16x16x32_f16(ah0, bh[nf], acc[2 * mg][nf], 0, 0, 0);
                    acc[2 * mg + 1][nf] = __builtin_amdgcn_mfma_f32_16x16x32_f16(ah1, bh[nf], acc[2 * mg + 1][nf], 0, 0, 0);
                }
#pragma unroll
                for (int nf = 0; nf < 4; ++nf) {
                    acc[2 * mg][nf]     = __builtin_amdgcn_mfma_f32_16x16x32_f16(ah0, bl[nf], acc[2 * mg][nf], 0, 0, 0);
                    acc[2 * mg + 1][nf] = __builtin_amdgcn_mfma_f32_16x16x32_f16(ah1, bl[nf], acc[2 * mg + 1][nf], 0, 0, 0);
                }
#pragma unroll
                for (int nf = 0; nf < 4; ++nf) {
                    acc[2 * mg][nf]     = __builtin_amdgcn_mfma_f32_16x16x32_f16(al0, bh[nf], acc[2 * mg][nf], 0, 0, 0);
                    acc[2 * mg + 1][nf] = __builtin_amdgcn_mfma_f32_16x16x32_f16(al1, bh[nf], acc[2 * mg + 1][nf], 0, 0, 0);
                }
                __builtin_amdgcn_s_setprio(0);
            }
            // drain: loads here are ~1 MFMA-cluster old -> near-free
            asm volatile("s_waitcnt vmcnt(0)" ::: "memory");
        }
        if (kt < 15) {
            __builtin_amdgcn_s_barrier();
            asm volatile("" ::: "memory");
        }
    }
}

// Z1 = x@W1^T + b_ih1 + b_hh1 (x pairs staged; W1 pairs direct-to-reg)
__global__ __launch_bounds__(512, 2) void k_z1(
    const f16* __restrict__ xhi, const f16* __restrict__ xlo,
    const f16* __restrict__ W1hi, const f16* __restrict__ W1lo,
    const float* __restrict__ bih1, const float* __restrict__ bhh1,
    float* __restrict__ Z1)
{
    __shared__ __align__(16) char sm[2 * BUFSZ];
    int m0, hc0; block_tile(m0, hc0);
    f32x4 acc[8][4];
#pragma unroll
    for (int a = 0; a < 8; ++a)
#pragma unroll
        for (int b = 0; b < 4; ++b) acc[a][b] = (f32x4){0.f, 0.f, 0.f, 0.f};
    passK64<true>(xhi, xlo, W1hi, W1lo, nullptr, m0, hc0, acc, sm);

    const int tid = threadIdx.x, lane = tid & 63, wid = tid >> 6;
    const int wm = (wid >> 2) * 128, wnb = wid & 3, l15 = lane & 15, lk = lane >> 4;
    const int hc = hc0 + wnb * 16 + l15;
#pragma unroll
    for (int mf = 0; mf < 8; ++mf)
#pragma unroll
        for (int r = 0; r < 4; ++r) {
            const int row = m0 + wm + mf * 16 + lk * 4 + r;
#pragma unroll
            for (int g = 0; g < 4; ++g) {
                const int R = g * 1024 + hc;
                Z1[(size_t)row * 4096 + R] = acc[mf][g][r] + bih1[R] + bhh1[R];
            }
        }
}

// Layer-1 cell: gates = Z1 (+flag col @step0) + h1@Whh1^T
__global__ __launch_bounds__(512, 2) void k_stepA(
    const float* __restrict__ Z1, const float* __restrict__ Whh1,
    const f16* __restrict__ h1hi_in, const f16* __restrict__ h1lo_in,
    const float* __restrict__ flagcol, float* __restrict__ c1,
    f16* __restrict__ h1hi_out, f16* __restrict__ h1lo_out,
    f16* __restrict__ acthi, f16* __restrict__ actlo,
    const unsigned* __restrict__ cnt_prev, int step)
{
    if (step > 0 && cnt_prev[0] == 0u) return;
    __shared__ __align__(16) char sm[2 * BUFSZ];
    int m0, hc0; block_tile(m0, hc0);
    f32x4 acc[8][4];
#pragma unroll
    for (int a = 0; a < 8; ++a)
#pragma unroll
        for (int b = 0; b < 4; ++b) acc[a][b] = (f32x4){0.f, 0.f, 0.f, 0.f};
    if (step > 0)
        passK64<false>(h1hi_in, h1lo_in, nullptr, nullptr, Whh1, m0, hc0, acc, sm);

    const int tid = threadIdx.x, lane = tid & 63, wid = tid >> 6;
    const int wm = (wid >> 2) * 128, wnb = wid & 3, l15 = lane & 15, lk = lane >> 4;
    const int hc = hc0 + wnb * 16 + l15;
#pragma unroll
    for (int mf = 0; mf < 8; ++mf)
#pragma unroll
        for (int r = 0; r < 4; ++r) {
            const int row = m0 + wm + mf * 16 + lk * 4 + r;
            float p[4];
#pragma unroll
            for (int g = 0; g < 4; ++g) {
                const int R = g * 1024 + hc;
                p[g] = acc[mf][g][r] + Z1[(size_t)row * 4096 + R];
                if (step == 0) p[g] += flagcol[R];
            }
            const float ig = sigmoidf_(p[0]);
            const float fg = sigmoidf_(p[1]);
            const float gg = tanhf(p[2]);
            const float og = sigmoidf_(p[3]);
            const int idx = row * 1024 + hc;
            const float cold = (step == 0) ? 0.0f : c1[idx];
            const float cn = fg * cold + ig * gg;
            c1[idx] = cn;
            const float h = og * tanhf(cn);
            const f16 hh = (f16)h;
            const f16 hl = (f16)(h - (float)hh);
            h1hi_out[idx] = hh; h1lo_out[idx] = hl;
            const bool pos = h > 0.0f;
            acthi[idx] = pos ? hh : (f16)0.0f;
            actlo[idx] = pos ? hl : (f16)0.0f;
        }
}

// Layer-2 cell: gates = b2 + act@Wih2^T + h2@Whh2^T
__global__ __launch_bounds__(512, 2) void k_stepB(
    const f16* __restrict__ acthi, const f16* __restrict__ actlo,
    const float* __restrict__ Wih2,
    const f16* __restrict__ h2hi_in, const f16* __restrict__ h2lo_in,
    const float* __restrict__ Whh2,
    const float* __restrict__ bih2, const float* __restrict__ bhh2,
    float* __restrict__ c2, f16* __restrict__ h2hi_out, f16* __restrict__ h2lo_out,
    const unsigned* __restrict__ cnt_prev, int step)
{
    if (step > 0 && cnt_prev[0] == 0u) return;
    __shared__ __align__(16) char sm[2 * BUFSZ];
    int m0, hc0; block_tile(m0, hc0);
    f32x4 acc[8][4];
#pragma unroll
    for (int a = 0; a < 8; ++a)
#pragma unroll
        for (int b = 0; b < 4; ++b) acc[a][b] = (f32x4){0.f, 0.f, 0.f, 0.f};
    passK64<false>(acthi, actlo, nullptr, nullptr, Wih2, m0, hc0, acc, sm);
    if (step > 0)
        passK64<false>(h2hi_in, h2lo_in, nullptr, nullptr, Whh2, m0, hc0, acc, sm);

    const int tid = threadIdx.x, lane = tid & 63, wid = tid >> 6;
    const int wm = (wid >> 2) * 128, wnb = wid & 3, l15 = lane & 15, lk = lane >> 4;
    const int hc = hc0 + wnb * 16 + l15;
#pragma unroll
    for (int mf = 0; mf < 8; ++mf)
#pragma unroll
        for (int r = 0; r < 4; ++r) {
            const int row = m0 + wm + mf * 16 + lk * 4 + r;
            float p[4];
#pragma unroll
            for (int g = 0; g < 4; ++g) {
                const int R = g * 1024 + hc;
                p[g] = acc[mf][g][r] + bih2[R] + bhh2[R];
            }
            const float ig = sigmoidf_(p[0]);
            const float fg = sigmoidf_(p[1]);
            const float gg = tanhf(p[2]);
            const float og = sigmoidf_(p[3]);
            const int idx = row * 1024 + hc;
            const float cold = (step == 0) ? 0.0f : c2[idx];
            const float cn = fg * cold + ig * gg;
            c2[idx] = cn;
            const float h = og * tanhf(cn);
            const f16 hh = (f16)h;
            h2hi_out[idx] = hh;
            h2lo_out[idx] = (f16)(h - (float)hh);
        }
}

// Merged halting state machine + acc_out accumulate (one wave per row).
__global__ __launch_bounds__(256) void k_haltacc(
    const f16* __restrict__ h2hi, const f16* __restrict__ h2lo,
    const float* __restrict__ Whalt, const float* __restrict__ bhalt,
    float* __restrict__ halt, float* __restrict__ cont,
    float* __restrict__ ponder_out, unsigned* __restrict__ ctrl,
    float* __restrict__ acc_out,
    const unsigned* __restrict__ cnt_prev, int step)
{
    if (step > 0 && cnt_prev[0] == 0u) return;
    const int lane = threadIdx.x & 63;
    const int b = blockIdx.x * 4 + (threadIdx.x >> 6);
    const size_t base = (size_t)b * 1024;
    float sum = 0.0f;
    for (int k = lane; k < 1024; k += 64)
        sum += ((float)h2hi[base + k] + (float)h2lo[base + k]) * Whalt[k];
#pragma unroll
    for (int off = 32; off > 0; off >>= 1) sum += __shfl_down(sum, off, 64);
    float co = 0.0f;
    if (lane == 0) {
        const float sh = sigmoidf_(sum + bhalt[0]);
        if (cont[b] != 0.0f) {
            const float hn = halt[b] + sh;
            const bool ending = hn > 0.99f;
            co = sh + (ending ? (1.0f - hn) : 0.0f);
            halt[b] = hn;
            if (!ending) {
                ponder_out[b] += 1.0f;
                atomicAdd(&ctrl[step], 1u);
            } else {
                cont[b] = 0.0f;
            }
        }
        if (b == 0) ctrl[12] = (unsigned)(step + 1);
    }
    co = __shfl(co, 0, 64);
    if (step == 0 || co != 0.0f) {
        float4* dst = (float4*)(acc_out + base);
        const f16x4* hi4 = (const f16x4*)(h2hi + base);
        const f16x4* lo4 = (const f16x4*)(h2lo + base);
#pragma unroll
        for (int j = 0; j < 4; ++j) {
            const int i = lane + 64 * j;
            const f16x4 hv = hi4[i];
            const f16x4 lv = lo4[i];
            float4 d = (step == 0) ? (float4){0.f, 0.f, 0.f, 0.f} : dst[i];
            d.x = fmaf(co, (float)hv[0] + (float)lv[0], d.x);
            d.y = fmaf(co, (float)hv[1] + (float)lv[1], d.y);
            d.z = fmaf(co, (float)hv[2] + (float)lv[2], d.z);
            d.w = fmaf(co, (float)hv[3] + (float)lv[3], d.w);
            dst[i] = d;
        }
    }
}

__global__ __launch_bounds__(256) void k_small_init(
    float* __restrict__ halt, float* __restrict__ cont,
    float* __restrict__ ponder_out, unsigned* __restrict__ ctrl)
{
    const int b = blockIdx.x * 256 + threadIdx.x;
    if (b < 4096) { halt[b] = 0.0f; cont[b] = 1.0f; ponder_out[b] = 0.0f; }
    if (b < 16) ctrl[b] = 0u;
}

// flat fp32 -> f16 hi/lo pairs (4096*1024 elements)
__global__ __launch_bounds__(256) void k_split_flat(
    const float* __restrict__ src, f16* __restrict__ hi, f16* __restrict__ lo)
{
    const size_t i = ((size_t)blockIdx.x * 256 + threadIdx.x) * 4;
    const float4 v = *(const float4*)(src + i);
    const f16 s0 = (f16)v.x, s1 = (f16)v.y, s2 = (f16)v.z, s3 = (f16)v.w;
    const f16x4 hv = {s0, s1, s2, s3};
    const f16x4 lw = {(f16)(v.x - (float)s0), (f16)(v.y - (float)s1),
                      (f16)(v.z - (float)s2), (f16)(v.w - (float)s3)};
    *(f16x4*)(hi + i) = hv;
    *(f16x4*)(lo + i) = lw;
}

// Wih1 [4096][1025]: cols 0..1023 -> pairs; col 1024 -> flagcol
__global__ __launch_bounds__(256) void k_split_wih1(
    const float* __restrict__ src, f16* __restrict__ hi, f16* __restrict__ lo,
    float* __restrict__ flagcol)
{
    const int t = blockIdx.x * 256 + threadIdx.x;
    const int row = t >> 8, c4 = (t & 255) << 2;
    const float* s = src + (size_t)row * 1025 + c4;
    const float v0 = s[0], v1 = s[1], v2 = s[2], v3 = s[3];
    const f16 s0 = (f16)v0, s1 = (f16)v1, s2 = (f16)v2, s3 = (f16)v3;
    const f16x4 hv = {s0, s1, s2, s3};
    const f16x4 lw = {(f16)(v0 - (float)s0), (f16)(v1 - (float)s1),
                      (f16)(v2 - (float)s2), (f16)(v3 - (float)s3)};
    const size_t di = (size_t)row * 1024 + c4;
    *(f16x4*)(hi + di) = hv;
    *(f16x4*)(lo + di) = lw;
    if ((t & 255) == 0) flagcol[row] = src[(size_t)row * 1025 + 1024];
}

__global__ __launch_bounds__(256) void k_fin1(
    const f16* __restrict__ h1hi0, const f16* __restrict__ h1hi1,
    const f16* __restrict__ h1lo0, const f16* __restrict__ h1lo1,
    const f16* __restrict__ h2hi0, const f16* __restrict__ h2hi1,
    const f16* __restrict__ h2lo0, const f16* __restrict__ h2lo1,
    const float* __restrict__ c1s, const float* __restrict__ c2s,
    const float* __restrict__ halt, const float* __restrict__ cont,
    const unsigned* __restrict__ ctrl, float* __restrict__ out)
{
    const int par = (int)(ctrl[12] & 1u);
    const f16* h1h = par ? h1hi1 : h1hi0;
    const f16* h1l = par ? h1lo1 : h1lo0;
    const f16* h2h = par ? h2hi1 : h2hi0;
    const f16* h2l = par ? h2lo1 : h2lo0;
    const int b = blockIdx.x;
    const float rem = (cont[b] != 0.0f) ? (1.0f - halt[b]) : 0.0f;
    const int base = b * 1024;
    for (int i = threadIdx.x; i < 1024; i += 256) {
        const float h1v = (float)h1h[base + i] + (float)h1l[base + i];
        const float h2v = (float)h2h[base + i] + (float)h2l[base + i];
        out[O_H1 + base + i] = h1v;
        out[O_C1 + base + i] = c1s[base + i];
        out[O_H2 + base + i] = h2v;
        out[O_C2 + base + i] = c2s[base + i];
        if (rem != 0.0f) out[O_ACC + base + i] += rem * h2v;
    }
}

__global__ __launch_bounds__(256) void k_fin2(
    const float* __restrict__ halt, float* __restrict__ out)
{
    __shared__ float red[256];
    float s = 0.0f;
    for (int i = threadIdx.x; i < 4096; i += 256) s += halt[i];
    red[threadIdx.x] = s;
    __syncthreads();
    for (int w = 128; w > 0; w >>= 1) {
        if (threadIdx.x < w) red[threadIdx.x] += red[threadIdx.x + w];
        __syncthreads();
    }
    if (threadIdx.x == 0) out[O_PCOST] = -0.01f * (red[0] * (1.0f / 4096.0f));
}

extern "C" void kernel_launch(void* const* d_in, const int* in_sizes, int n_in,
                              void* d_out, int out_size, void* d_ws, size_t ws_size,
                              hipStream_t stream) {
    const float* inputs = (const float*)d_in[0];
    const float* W_ih1  = (const float*)d_in[1];
    const float* W_hh1  = (const float*)d_in[2];
    const float* b_ih1  = (const float*)d_in[3];
    const float* b_hh1  = (const float*)d_in[4];
    const float* W_ih2  = (const float*)d_in[5];
    const float* W_hh2  = (const float*)d_in[6];
    const float* b_ih2  = (const float*)d_in[7];
    const float* b_hh2  = (const float*)d_in[8];
    const float* W_halt = (const float*)d_in[9];
    const float* b_halt = (const float*)d_in[10];

    float* out = (float*)d_out;
    float* Z1  = out + O_H1;                  // 64 MB in d_out's dead state region

    char* wsb = (char*)d_ws;
    float* c1s = (float*)(wsb + WS_C1);
    float* c2s = (float*)(wsb + WS_C2);
    f16* h1hi[2] = { (f16*)(wsb + WS_H1HI0), (f16*)(wsb + WS_H1HI1) };
    f16* h1lo[2] = { (f16*)(wsb + WS_H1LO0), (f16*)(wsb + WS_H1LO1) };
    f16* h2hi[2] = { (f16*)(wsb + WS_H2HI0), (f16*)(wsb + WS_H2HI1) };
    f16* h2lo[2] = { (f16*)(wsb + WS_H2LO0), (f16*)(wsb + WS_H2LO1) };
    f16* acthi   = (f16*)(wsb + WS_ACTHI);
    f16* actlo   = (f16*)(wsb + WS_ACTLO);
    float* halt    = (float*)(wsb + WS_MISC);
    float* cont    = halt + 4096;
    float* coef    = cont + 4096;
    float* flagcol = coef + 4096;
    unsigned* ctrl = (unsigned*)(flagcol + 4096);

    // x / W1 pairs live in the step-0-dead h ping-pong set 0 slots
    f16* xhi  = h1hi[0]; f16* xlo  = h1lo[0];
    f16* W1hi = h2hi[0]; f16* W1lo = h2lo[0];

    k_small_init<<<16, 256, 0, stream>>>(halt, cont, out + O_PSTEP, ctrl);

    k_split_wih1<<<4096, 256, 0, stream>>>(W_ih1, W1hi, W1lo, flagcol);
    k_split_flat<<<4096, 256, 0, stream>>>(inputs, xhi, xlo);
    k_z1<<<256, 512, 0, stream>>>(xhi, xlo, W1hi, W1lo, b_ih1, b_hh1, Z1);

    for (int s = 0; s < TSTEPS; ++s) {
        const int wsel = (s & 1) ? 0 : 1;
        const int rsel = 1 - wsel;
        const unsigned* cnt_prev = ctrl + (s > 0 ? s - 1 : 0);

        k_stepA<<<256, 512, 0, stream>>>(Z1, W_hh1, h1hi[rsel], h1lo[rsel],
                                         flagcol, c1s,
                                         h1hi[wsel], h1lo[wsel], acthi, actlo,
                                         cnt_prev, s);
        k_stepB<<<256, 512, 0, stream>>>(acthi, actlo, W_ih2,
                                         h2hi[rsel], h2lo[rsel], W_hh2,
                                         b_ih2, b_hh2, c2s,
                                         h2hi[wsel], h2lo[wsel],
                                         cnt_prev, s);
        k_haltacc<<<1024, 256, 0, stream>>>(h2hi[wsel], h2lo[wsel], W_halt, b_halt,
                                            halt, cont, out + O_PSTEP, ctrl,
                                            out + O_ACC, cnt_prev, s);
    }

    k_fin1<<<4096, 256, 0, stream>>>(h1hi[0], h1hi[1], h1lo[0], h1lo[1],
                                     h2hi[0], h2hi[1], h2lo[0], h2lo[1],
                                     c1s, c2s, halt, cont, ctrl, out);
    k_fin2<<<1, 256, 0, stream>>>(halt, out);
}